// Round 6
// baseline (93.394 us; speedup 1.0000x reference)
//
#include <hip/hip_runtime.h>
#include <math.h>

namespace {
constexpr int B = 2;
constexpr int S = 2048;
constexpr int D = 2048;
constexpr int T = 8;              // rows per block (smaller window -> <=128 VGPR -> 2 blocks/CU)
constexpr int G = 4;              // rows per pipeline group
constexpr float EPS = 1e-6f;
constexpr int THREADS = 512;      // 512 threads x float4 = 2048 = D
constexpr int NROWS = T + 5;      // 13 rows resident per block

typedef float floatx4 __attribute__((ext_vector_type(4)));  // native vec for nontemporal builtin

__global__ __launch_bounds__(THREADS, 4) void gated_kernel(
    const float* __restrict__ x,
    const float* __restrict__ weight,   // (D, 4) row-major
    const float* __restrict__ alpha,    // (3,)
    const float* __restrict__ rms_w,    // (D,)
    float* __restrict__ out)
{
    const int blk = blockIdx.x;          // 0 .. B*(S/T)-1, S/T = 256
    const int b   = blk >> 8;
    const int s0  = (blk & 255) << 3;    // * T
    const int tid = threadIdx.x;
    const int d   = tid << 2;
    const int wave = tid >> 6;
    const int lane = tid & 63;

    const float* xb = x + ((size_t)b * S) * D;

    // xr[j][c] = x[b, s0-5+j, d+c], zero-padded for negative rows.
    // Row s0+t is xr[t+5]; x[s0+t-k] = xr[t+5-k]; x[s0+t-k-2] = xr[t+3-k].
    float xr[NROWS][4];
#pragma unroll
    for (int j = 0; j < NROWS; ++j) {
        const int ss = s0 - 5 + j;       // block-uniform -> no divergence
        if (ss >= 0) {
            const float4 v = *reinterpret_cast<const float4*>(xb + (size_t)ss * D + d);
            xr[j][0] = v.x; xr[j][1] = v.y; xr[j][2] = v.z; xr[j][3] = v.w;
        } else {
            xr[j][0] = xr[j][1] = xr[j][2] = xr[j][3] = 0.f;
        }
    }

    // Only w^2 is ever needed.
    float wsq[4][4];
#pragma unroll
    for (int c = 0; c < 4; ++c) {
        const float4 t4 = *reinterpret_cast<const float4*>(weight + ((size_t)(d + c) << 2));
        wsq[c][0] = t4.x * t4.x; wsq[c][1] = t4.y * t4.y;
        wsq[c][2] = t4.z * t4.z; wsq[c][3] = t4.w * t4.w;
    }

    const float4 rv = *reinterpret_cast<const float4*>(rms_w + d);
    const float rms[4] = {rv.x, rv.y, rv.z, rv.w};

    // pl[row][value][wave]: value 0..2 = dot k=1..3, 3..6 = sumsq k=0..3
    __shared__ float pl[T][8][8];
    __shared__ float cbc[T][4];

    float* ob = out + ((size_t)b * S + (size_t)s0) * D + d;

#pragma unroll
    for (int g = 0; g < T / G; ++g) {
        // ---- reduce G rows ----
#pragma unroll
        for (int tg = 0; tg < G; ++tg) {
            const int t = g * G + tg;
            float v[8];
#pragma unroll
            for (int k = 1; k < 4; ++k) {
                float dk = 0.f;
#pragma unroll
                for (int c = 0; c < 4; ++c) dk += xr[t + 5][c] * xr[t + 5 - k][c];
                v[k - 1] = dk;
            }
#pragma unroll
            for (int k = 0; k < 4; ++k) {
                float sk = 0.f;
#pragma unroll
                for (int c = 0; c < 4; ++c) {
                    const float gg = xr[t + 5 - k][c] * xr[t + 3 - k][c];
                    sk += gg * gg * wsq[c][k];
                }
                v[3 + k] = sk;
            }
            v[7] = 0.f;

            // Reduce-scatter butterfly: 8 values over 64 lanes in 10 shfl.
            const bool b0 = (lane & 1), b1 = (lane & 2), b2 = (lane & 4);
            float w4[4];
#pragma unroll
            for (int i = 0; i < 4; ++i) {
                const float keep  = b0 ? v[i + 4] : v[i];
                const float other = b0 ? v[i]     : v[i + 4];
                w4[i] = keep + __shfl_xor(other, 1, 64);
            }
            float u2[2];
#pragma unroll
            for (int i = 0; i < 2; ++i) {
                const float keep  = b1 ? w4[i + 2] : w4[i];
                const float other = b1 ? w4[i]     : w4[i + 2];
                u2[i] = keep + __shfl_xor(other, 2, 64);
            }
            {
                const float keep  = b2 ? u2[1] : u2[0];
                const float other = b2 ? u2[0] : u2[1];
                float r = keep + __shfl_xor(other, 4, 64);
                r += __shfl_down(r, 8, 64);
                r += __shfl_down(r, 16, 64);
                r += __shfl_down(r, 32, 64);
                if (lane < 8) {
                    const int vidx = ((lane & 1) << 2) | (lane & 2) | ((lane >> 2) & 1);
                    pl[t][vidx][wave] = r;
                }
            }
        }
        __syncthreads();

        // ---- cbc for this group's G rows (G*4 = 16 threads) ----
        if (tid < G * 4) {
            const int t = g * G + (tid >> 2), k = tid & 3;
            float ss = 0.f;
#pragma unroll
            for (int w = 0; w < 8; ++w) ss += pl[t][3 + k][w];
            float lam = 1.f;
            if (k > 0) {
                float dd = 0.f;
#pragma unroll
                for (int w = 0; w < 8; ++w) dd += pl[t][k - 1][w];
                lam = tanhf(dd * alpha[k - 1]);
            }
            cbc[t][k] = lam * rsqrtf(ss * (1.f / (float)D) + EPS);
        }
        __syncthreads();

        // ---- epilogue + NT store for this group's G rows ----
#pragma unroll
        for (int tg = 0; tg < G; ++tg) {
            const int t = g * G + tg;
            const float c0 = cbc[t][0], c1 = cbc[t][1], c2 = cbc[t][2], c3 = cbc[t][3];
            floatx4 ov;
#pragma unroll
            for (int c = 0; c < 4; ++c) {
                const float acc = c0 * wsq[c][0] * (xr[t + 5][c] * xr[t + 3][c])
                                + c1 * wsq[c][1] * (xr[t + 4][c] * xr[t + 2][c])
                                + c2 * wsq[c][2] * (xr[t + 3][c] * xr[t + 1][c])
                                + c3 * wsq[c][3] * (xr[t + 2][c] * xr[t + 0][c]);
                ov[c] = xr[t + 5][c] + rms[c] * acc;
            }
            __builtin_nontemporal_store(ov, reinterpret_cast<floatx4*>(ob + (size_t)t * D));
        }
    }
}
} // namespace

extern "C" void kernel_launch(void* const* d_in, const int* in_sizes, int n_in,
                              void* d_out, int out_size, void* d_ws, size_t ws_size,
                              hipStream_t stream) {
    const float* x      = (const float*)d_in[0];
    const float* weight = (const float*)d_in[1];
    const float* alpha  = (const float*)d_in[2];
    const float* rms_w  = (const float*)d_in[3];
    float* out          = (float*)d_out;

    gated_kernel<<<dim3(B * (S / T)), dim3(THREADS), 0, stream>>>(x, weight, alpha, rms_w, out);
}